// Round 1
// baseline (3292.139 us; speedup 1.0000x reference)
//
#include <hip/hip_runtime.h>
#include <math.h>

#define INC 128
#define F1 256
#define HEADS 4
#define NEG_SLOPE 0.2f

// ---------------- GEMM1: h1 = x @ W1, fused att dot products ----------------
// grid: ceil(N/16) blocks, 256 threads. wave handles 4 rows x 256 cols.
__global__ __launch_bounds__(256, 1) void gemm1_kernel(
    const float* __restrict__ x, const float* __restrict__ W1,
    const float* __restrict__ att_s, const float* __restrict__ att_d,
    float* __restrict__ h1, float* __restrict__ a_src, float* __restrict__ a_dst,
    int N)
{
    __shared__ float wlds[INC * F1];  // 128 KB
    for (int i = threadIdx.x * 4; i < INC * F1; i += 256 * 4) {
        *(float4*)&wlds[i] = *(const float4*)&W1[i];
    }
    int wave = threadIdx.x >> 6;
    int lane = threadIdx.x & 63;
    int c4 = lane * 4;  // starting column (of 4 consecutive)
    // attention vectors for my 4 columns
    float4 as4 = *(const float4*)&att_s[c4];
    float4 ad4 = *(const float4*)&att_d[c4];
    __syncthreads();

    int row0 = blockIdx.x * 16 + wave * 4;
    float acc[4][4] = {};
    for (int kk = 0; kk < INC; kk += 4) {
        float4 xv[4];
        #pragma unroll
        for (int r = 0; r < 4; ++r) {
            int row = row0 + r;
            xv[r] = (row < N) ? *(const float4*)&x[(size_t)row * INC + kk]
                              : make_float4(0.f, 0.f, 0.f, 0.f);
        }
        #pragma unroll
        for (int dk = 0; dk < 4; ++dk) {
            float4 wv = *(float4*)&wlds[(kk + dk) * F1 + c4];
            #pragma unroll
            for (int r = 0; r < 4; ++r) {
                float xs = dk == 0 ? xv[r].x : dk == 1 ? xv[r].y : dk == 2 ? xv[r].z : xv[r].w;
                acc[r][0] = fmaf(xs, wv.x, acc[r][0]);
                acc[r][1] = fmaf(xs, wv.y, acc[r][1]);
                acc[r][2] = fmaf(xs, wv.z, acc[r][2]);
                acc[r][3] = fmaf(xs, wv.w, acc[r][3]);
            }
        }
    }
    int head = lane >> 4;  // cols c4..c4+3 lie in head (lane*4)/64
    #pragma unroll
    for (int r = 0; r < 4; ++r) {
        int row = row0 + r;
        if (row >= N) continue;
        float4 hv = make_float4(acc[r][0], acc[r][1], acc[r][2], acc[r][3]);
        *(float4*)&h1[(size_t)row * F1 + c4] = hv;
        float ps = acc[r][0] * as4.x + acc[r][1] * as4.y + acc[r][2] * as4.z + acc[r][3] * as4.w;
        float pd = acc[r][0] * ad4.x + acc[r][1] * ad4.y + acc[r][2] * ad4.z + acc[r][3] * ad4.w;
        #pragma unroll
        for (int o = 8; o > 0; o >>= 1) {
            ps += __shfl_xor(ps, o);
            pd += __shfl_xor(pd, o);
        }
        if ((lane & 15) == 0) {
            a_src[row * HEADS + head] = ps;
            a_dst[row * HEADS + head] = pd;
        }
    }
}

// ---------------- CSR build ----------------
__global__ void hist_kernel(const int* __restrict__ ei, int* __restrict__ deg,
                            int E, int Etot)
{
    int e = blockIdx.x * blockDim.x + threadIdx.x;
    if (e >= Etot) return;
    int d = (e < E) ? ei[E + e] : (e - E);
    atomicAdd(&deg[d], 1);
}

__global__ void scan1_kernel(const int* __restrict__ deg, int* __restrict__ incl,
                             int* __restrict__ bsum, int N)
{
    __shared__ int tmp[256];
    int i = blockIdx.x * 256 + threadIdx.x;
    int v = (i < N) ? deg[i] : 0;
    tmp[threadIdx.x] = v;
    __syncthreads();
    for (int o = 1; o < 256; o <<= 1) {
        int add = (threadIdx.x >= o) ? tmp[threadIdx.x - o] : 0;
        __syncthreads();
        tmp[threadIdx.x] += add;
        __syncthreads();
    }
    if (i < N) incl[i] = tmp[threadIdx.x];
    if (threadIdx.x == 255) bsum[blockIdx.x] = tmp[255];
}

__global__ void scan2_kernel(int* __restrict__ bsum, int nb)
{
    __shared__ int tmp[256];
    int v = (threadIdx.x < nb) ? bsum[threadIdx.x] : 0;
    tmp[threadIdx.x] = v;
    __syncthreads();
    for (int o = 1; o < 256; o <<= 1) {
        int add = (threadIdx.x >= o) ? tmp[threadIdx.x - o] : 0;
        __syncthreads();
        tmp[threadIdx.x] += add;
        __syncthreads();
    }
    if (threadIdx.x < nb) bsum[threadIdx.x] = tmp[threadIdx.x] - v;  // exclusive
}

__global__ void scan3_kernel(const int* __restrict__ deg, const int* __restrict__ incl,
                             const int* __restrict__ bsum, int* __restrict__ off,
                             int* __restrict__ cursor, int N, int Etot)
{
    int i = blockIdx.x * 256 + threadIdx.x;
    if (i < N) {
        int ex = incl[i] - deg[i] + bsum[blockIdx.x];
        off[i] = ex;
        cursor[i] = ex;
    } else if (i == N) {
        off[N] = Etot;
    }
}

__global__ void fill_kernel(const int* __restrict__ ei, int* __restrict__ cursor,
                            int* __restrict__ esrc, int E, int Etot)
{
    int e = blockIdx.x * blockDim.x + threadIdx.x;
    if (e >= Etot) return;
    int s, d;
    if (e < E) { s = ei[e]; d = ei[E + e]; }
    else       { s = d = e - E; }
    int pos = atomicAdd(&cursor[d], 1);
    esrc[pos] = s;
}

// ---------------- Layer-1 aggregation + bias + ELU + z = out1 @ W2 ----------------
// grid: N blocks, 256 threads. wave w = head w; thread t = channel t.
__global__ __launch_bounds__(256) void agg1_kernel(
    const float* __restrict__ h1, const float* __restrict__ a_src,
    const float* __restrict__ a_dst, const int* __restrict__ off,
    const int* __restrict__ esrc, const float* __restrict__ bias1,
    const float* __restrict__ W2, float* __restrict__ out1,
    float* __restrict__ z, int N)
{
    int n = blockIdx.x;
    int tid = threadIdx.x;
    int head = tid >> 6;
    int lane = tid & 63;
    int beg = off[n], end = off[n + 1];
    float ad = a_dst[n * HEADS + head];

    // online softmax (max + denom) per head, lane-parallel over edges
    float m = -1e30f, s = 0.f;
    for (int i = beg + lane; i < end; i += 64) {
        int sN = esrc[i];
        float ev = a_src[sN * HEADS + head] + ad;
        ev = ev > 0.f ? ev : NEG_SLOPE * ev;
        float nm = fmaxf(m, ev);
        s = s * __expf(m - nm) + __expf(ev - nm);
        m = nm;
    }
    #pragma unroll
    for (int o = 32; o > 0; o >>= 1) {
        float om = __shfl_xor(m, o);
        float os = __shfl_xor(s, o);
        float nm = fmaxf(m, om);
        s = s * __expf(m - nm) + os * __expf(om - nm);
        m = nm;
    }
    float inv = 1.f / s;

    // weighted gather
    float acc = 0.f;
    for (int i = beg; i < end; ++i) {
        int sN = esrc[i];
        float ev = a_src[sN * HEADS + head] + ad;
        ev = ev > 0.f ? ev : NEG_SLOPE * ev;
        float al = __expf(ev - m) * inv;
        acc = fmaf(al, h1[(size_t)sN * F1 + tid], acc);
    }
    float o1 = acc + bias1[tid];
    o1 = o1 > 0.f ? o1 : __expf(o1) - 1.f;  // ELU
    out1[(size_t)n * F1 + tid] = o1;

    // z[n] = sum_t out1[n][t] * W2[t]
    float p = o1 * W2[tid];
    #pragma unroll
    for (int o = 32; o > 0; o >>= 1) p += __shfl_xor(p, o);
    __shared__ float zred[4];
    if (lane == 0) zred[head] = p;
    __syncthreads();
    if (tid == 0) z[n] = zred[0] + zred[1] + zred[2] + zred[3];
}

// ---------------- Layer-2 aggregation: one wave per node ----------------
__global__ __launch_bounds__(256) void agg2_kernel(
    const float* __restrict__ z, const int* __restrict__ off,
    const int* __restrict__ esrc, const float* __restrict__ att_s2,
    const float* __restrict__ att_d2, const float* __restrict__ bias2,
    float* __restrict__ out, int N)
{
    int wave = threadIdx.x >> 6;
    int lane = threadIdx.x & 63;
    int n = blockIdx.x * 4 + wave;
    if (n >= N) return;
    float as2 = att_s2[0], ad2 = att_d2[0];
    int beg = off[n], end = off[n + 1];
    float dstterm = z[n] * ad2;
    float m = -1e30f, s = 0.f, w = 0.f;
    for (int i = beg + lane; i < end; i += 64) {
        int sN = esrc[i];
        float zv = z[sN];
        float ev = zv * as2 + dstterm;
        ev = ev > 0.f ? ev : NEG_SLOPE * ev;
        float nm = fmaxf(m, ev);
        float c0 = __expf(m - nm), c1 = __expf(ev - nm);
        s = s * c0 + c1;
        w = w * c0 + c1 * zv;
        m = nm;
    }
    #pragma unroll
    for (int o = 32; o > 0; o >>= 1) {
        float om = __shfl_xor(m, o), os = __shfl_xor(s, o), ow = __shfl_xor(w, o);
        float nm = fmaxf(m, om);
        float c0 = __expf(m - nm), c1 = __expf(om - nm);
        s = s * c0 + os * c1;
        w = w * c0 + ow * c1;
        m = nm;
    }
    if (lane == 0) out[n] = w / s + bias2[0];
}

// ---------------- launch ----------------
extern "C" void kernel_launch(void* const* d_in, const int* in_sizes, int n_in,
                              void* d_out, int out_size, void* d_ws, size_t ws_size,
                              hipStream_t stream)
{
    const float* x        = (const float*)d_in[0];
    const int*   ei       = (const int*)d_in[1];
    const float* W1       = (const float*)d_in[2];
    const float* att_src1 = (const float*)d_in[3];
    const float* att_dst1 = (const float*)d_in[4];
    const float* bias1    = (const float*)d_in[5];
    const float* W2       = (const float*)d_in[6];
    const float* att_src2 = (const float*)d_in[7];
    const float* att_dst2 = (const float*)d_in[8];
    const float* bias2    = (const float*)d_in[9];
    float* out = (float*)d_out;

    int N = in_sizes[0] / INC;
    int E = in_sizes[1] / 2;
    int Etot = E + N;

    // workspace carve-up
    char* p = (char*)d_ws;
    auto alloc = [&](size_t bytes) {
        void* r = (void*)p;
        p += (bytes + 255) & ~(size_t)255;
        return r;
    };
    float* h1     = (float*)alloc((size_t)N * F1 * 4);
    float* out1   = (float*)alloc((size_t)N * F1 * 4);
    float* a_src1 = (float*)alloc((size_t)N * HEADS * 4);
    float* a_dst1 = (float*)alloc((size_t)N * HEADS * 4);
    float* z      = (float*)alloc((size_t)N * 4);
    int* deg    = (int*)alloc((size_t)N * 4);
    int* incl   = (int*)alloc((size_t)N * 4);
    int* off    = (int*)alloc((size_t)(N + 1) * 4);
    int* cursor = (int*)alloc((size_t)N * 4);
    int* bsum   = (int*)alloc(1024);
    int* esrc   = (int*)alloc((size_t)Etot * 4);

    hipMemsetAsync(deg, 0, (size_t)N * 4, stream);

    int nrt = (N + 15) / 16;
    gemm1_kernel<<<nrt, 256, 0, stream>>>(x, W1, att_src1, att_dst1, h1, a_src1, a_dst1, N);

    int egrid = (Etot + 255) / 256;
    hist_kernel<<<egrid, 256, 0, stream>>>(ei, deg, E, Etot);

    int nb = (N + 255) / 256;
    scan1_kernel<<<nb, 256, 0, stream>>>(deg, incl, bsum, N);
    scan2_kernel<<<1, 256, 0, stream>>>(bsum, nb);
    int nb1 = (N + 1 + 255) / 256;
    scan3_kernel<<<nb1, 256, 0, stream>>>(deg, incl, bsum, off, cursor, N, Etot);
    fill_kernel<<<egrid, 256, 0, stream>>>(ei, cursor, esrc, E, Etot);

    agg1_kernel<<<N, 256, 0, stream>>>(h1, a_src1, a_dst1, off, esrc, bias1, W2, out1, z, N);

    int ngrid2 = (N + 3) / 4;
    agg2_kernel<<<ngrid2, 256, 0, stream>>>(z, off, esrc, att_src2, att_dst2, bias2, out, N);
}

// Round 2
// 308.018 us; speedup vs baseline: 10.6881x; 10.6881x over previous
//
#include <hip/hip_runtime.h>
#include <math.h>

#define INC 128
#define F1 256
#define HEADS 4
#define NEG_SLOPE 0.2f
#define BM 32
#define BK 32

// ---------------- GEMM1: h1 = x @ W1, fused att dot products ----------------
// grid: ceil(N/32) blocks, 256 threads (4 waves). Wave w: rows w*8..w*8+7.
// Lane l: cols l*4..l*4+3. Per-lane acc[8][4].
__global__ __launch_bounds__(256, 4) void gemm1_kernel(
    const float* __restrict__ x, const float* __restrict__ W1,
    const float* __restrict__ att_s, const float* __restrict__ att_d,
    float* __restrict__ h1, float* __restrict__ a_src, float* __restrict__ a_dst,
    int N)
{
    __shared__ float ws[BK][F1];   // 32 KB
    __shared__ float xs[BK][36];   // transposed x tile, padded (4.6 KB)

    const int wave = threadIdx.x >> 6;
    const int lane = threadIdx.x & 63;
    const int c4 = lane << 2;
    const int row0 = blockIdx.x * BM;

    float acc[8][4] = {};

    for (int k0 = 0; k0 < INC; k0 += BK) {
        // stage x tile (transposed): thread t -> row t>>3, k-quad (t&7)*4
        {
            int r = threadIdx.x >> 3;
            int kq = (threadIdx.x & 7) << 2;
            int row = row0 + r;
            float4 v = (row < N) ? *(const float4*)&x[(size_t)row * INC + k0 + kq]
                                 : make_float4(0.f, 0.f, 0.f, 0.f);
            xs[kq + 0][r] = v.x;
            xs[kq + 1][r] = v.y;
            xs[kq + 2][r] = v.z;
            xs[kq + 3][r] = v.w;
        }
        // stage W tile: 32 k x 256 cols = 2048 float4 -> 8 per thread, coalesced
        #pragma unroll
        for (int i = 0; i < 8; ++i) {
            int fi = (threadIdx.x + i * 256) << 2;
            int kk = fi >> 8;
            int c = fi & 255;
            *(float4*)&ws[kk][c] = *(const float4*)&W1[(size_t)(k0 + kk) * F1 + c];
        }
        __syncthreads();

        #pragma unroll 4
        for (int kk = 0; kk < BK; ++kk) {
            float4 wv = *(float4*)&ws[kk][c4];
            float4 xa = *(float4*)&xs[kk][wave << 3];
            float4 xb = *(float4*)&xs[kk][(wave << 3) + 4];
            float xr[8] = {xa.x, xa.y, xa.z, xa.w, xb.x, xb.y, xb.z, xb.w};
            #pragma unroll
            for (int r = 0; r < 8; ++r) {
                acc[r][0] = fmaf(xr[r], wv.x, acc[r][0]);
                acc[r][1] = fmaf(xr[r], wv.y, acc[r][1]);
                acc[r][2] = fmaf(xr[r], wv.z, acc[r][2]);
                acc[r][3] = fmaf(xr[r], wv.w, acc[r][3]);
            }
        }
        __syncthreads();
    }

    // epilogue: store h1 + attention dot products
    float4 as4 = *(const float4*)&att_s[c4];
    float4 ad4 = *(const float4*)&att_d[c4];
    int head = lane >> 4;
    #pragma unroll
    for (int r = 0; r < 8; ++r) {
        int row = row0 + (wave << 3) + r;
        if (row >= N) continue;
        float4 hv = make_float4(acc[r][0], acc[r][1], acc[r][2], acc[r][3]);
        *(float4*)&h1[(size_t)row * F1 + c4] = hv;
        float ps = acc[r][0] * as4.x + acc[r][1] * as4.y + acc[r][2] * as4.z + acc[r][3] * as4.w;
        float pd = acc[r][0] * ad4.x + acc[r][1] * ad4.y + acc[r][2] * ad4.z + acc[r][3] * ad4.w;
        #pragma unroll
        for (int o = 8; o > 0; o >>= 1) {
            ps += __shfl_xor(ps, o);
            pd += __shfl_xor(pd, o);
        }
        if ((lane & 15) == 0) {
            a_src[row * HEADS + head] = ps;
            a_dst[row * HEADS + head] = pd;
        }
    }
}

// ---------------- CSR build ----------------
__global__ void hist_kernel(const int* __restrict__ ei, int* __restrict__ deg,
                            int E, int Etot)
{
    int e = blockIdx.x * blockDim.x + threadIdx.x;
    if (e >= Etot) return;
    int d = (e < E) ? ei[E + e] : (e - E);
    atomicAdd(&deg[d], 1);
}

__global__ void scan1_kernel(const int* __restrict__ deg, int* __restrict__ incl,
                             int* __restrict__ bsum, int N)
{
    __shared__ int tmp[256];
    int i = blockIdx.x * 256 + threadIdx.x;
    int v = (i < N) ? deg[i] : 0;
    tmp[threadIdx.x] = v;
    __syncthreads();
    for (int o = 1; o < 256; o <<= 1) {
        int add = (threadIdx.x >= o) ? tmp[threadIdx.x - o] : 0;
        __syncthreads();
        tmp[threadIdx.x] += add;
        __syncthreads();
    }
    if (i < N) incl[i] = tmp[threadIdx.x];
    if (threadIdx.x == 255) bsum[blockIdx.x] = tmp[255];
}

__global__ void scan2_kernel(int* __restrict__ bsum, int nb)
{
    __shared__ int tmp[256];
    int v = (threadIdx.x < nb) ? bsum[threadIdx.x] : 0;
    tmp[threadIdx.x] = v;
    __syncthreads();
    for (int o = 1; o < 256; o <<= 1) {
        int add = (threadIdx.x >= o) ? tmp[threadIdx.x - o] : 0;
        __syncthreads();
        tmp[threadIdx.x] += add;
        __syncthreads();
    }
    if (threadIdx.x < nb) bsum[threadIdx.x] = tmp[threadIdx.x] - v;  // exclusive
}

__global__ void scan3_kernel(const int* __restrict__ deg, const int* __restrict__ incl,
                             const int* __restrict__ bsum, int* __restrict__ off,
                             int* __restrict__ cursor, int N, int Etot)
{
    int i = blockIdx.x * 256 + threadIdx.x;
    if (i < N) {
        int ex = incl[i] - deg[i] + bsum[blockIdx.x];
        off[i] = ex;
        cursor[i] = ex;
    } else if (i == N) {
        off[N] = Etot;
    }
}

__global__ void fill_kernel(const int* __restrict__ ei, int* __restrict__ cursor,
                            int* __restrict__ esrc, int E, int Etot)
{
    int e = blockIdx.x * blockDim.x + threadIdx.x;
    if (e >= Etot) return;
    int s, d;
    if (e < E) { s = ei[e]; d = ei[E + e]; }
    else       { s = d = e - E; }
    int pos = atomicAdd(&cursor[d], 1);
    esrc[pos] = s;
}

// ---------------- Layer-1 aggregation + bias + ELU + z = out1 @ W2 ----------------
// One WAVE per node. Lane l: head = l>>4, channels c4 = l*4 (float4).
__global__ __launch_bounds__(256) void agg1_kernel(
    const float* __restrict__ h1, const float* __restrict__ a_src,
    const float* __restrict__ a_dst, const int* __restrict__ off,
    const int* __restrict__ esrc, const float* __restrict__ bias1,
    const float* __restrict__ W2, float* __restrict__ z, int N)
{
    const int wave = threadIdx.x >> 6;
    const int lane = threadIdx.x & 63;
    const int n = blockIdx.x * 4 + wave;
    if (n >= N) return;

    const int beg = off[n], end = off[n + 1];
    const float4* a_src4 = (const float4*)a_src;
    const float4* h1f4 = (const float4*)h1;
    float4 ad4 = *(const float4*)&a_dst[n * HEADS];
    float ad[4] = {ad4.x, ad4.y, ad4.z, ad4.w};

    // phase 1: online softmax (max + denom) per head, lane-parallel over edges
    float m[4] = {-1e30f, -1e30f, -1e30f, -1e30f};
    float s[4] = {0.f, 0.f, 0.f, 0.f};
    for (int i = beg + lane; i < end; i += 64) {
        int sN = esrc[i];
        float4 a4 = a_src4[sN];
        float av[4] = {a4.x, a4.y, a4.z, a4.w};
        #pragma unroll
        for (int h = 0; h < 4; ++h) {
            float ev = av[h] + ad[h];
            ev = ev > 0.f ? ev : NEG_SLOPE * ev;
            float nm = fmaxf(m[h], ev);
            s[h] = s[h] * __expf(m[h] - nm) + __expf(ev - nm);
            m[h] = nm;
        }
    }
    #pragma unroll
    for (int o = 32; o > 0; o >>= 1) {
        #pragma unroll
        for (int h = 0; h < 4; ++h) {
            float om = __shfl_xor(m[h], o);
            float os = __shfl_xor(s[h], o);
            float nm = fmaxf(m[h], om);
            s[h] = s[h] * __expf(m[h] - nm) + os * __expf(om - nm);
            m[h] = nm;
        }
    }

    const int head = lane >> 4;
    float mh = m[head];
    float invh = 1.f / s[head];
    float adh = ad[head];

    // phase 2: weighted gather, one h1 row (1 KB) per edge via 64 x b128
    float4 acc = make_float4(0.f, 0.f, 0.f, 0.f);
    for (int i = beg; i < end; ++i) {
        int sN = esrc[i];
        float asv = a_src[sN * HEADS + head];
        float ev = asv + adh;
        ev = ev > 0.f ? ev : NEG_SLOPE * ev;
        float al = __expf(ev - mh) * invh;
        float4 hv = h1f4[(size_t)sN * 64 + lane];
        acc.x = fmaf(al, hv.x, acc.x);
        acc.y = fmaf(al, hv.y, acc.y);
        acc.z = fmaf(al, hv.z, acc.z);
        acc.w = fmaf(al, hv.w, acc.w);
    }

    // bias + ELU + dot with W2 (out1 never materialized; only z is needed)
    float4 b4 = *(const float4*)&bias1[lane << 2];
    float4 w24 = *(const float4*)&W2[lane << 2];
    float o0 = acc.x + b4.x, o1 = acc.y + b4.y, o2 = acc.z + b4.z, o3 = acc.w + b4.w;
    o0 = o0 > 0.f ? o0 : __expf(o0) - 1.f;
    o1 = o1 > 0.f ? o1 : __expf(o1) - 1.f;
    o2 = o2 > 0.f ? o2 : __expf(o2) - 1.f;
    o3 = o3 > 0.f ? o3 : __expf(o3) - 1.f;
    float p = o0 * w24.x + o1 * w24.y + o2 * w24.z + o3 * w24.w;
    #pragma unroll
    for (int o = 32; o > 0; o >>= 1) p += __shfl_xor(p, o);
    if (lane == 0) z[n] = p;
}

// ---------------- Layer-2 aggregation: one wave per node ----------------
__global__ __launch_bounds__(256) void agg2_kernel(
    const float* __restrict__ z, const int* __restrict__ off,
    const int* __restrict__ esrc, const float* __restrict__ att_s2,
    const float* __restrict__ att_d2, const float* __restrict__ bias2,
    float* __restrict__ out, int N)
{
    int wave = threadIdx.x >> 6;
    int lane = threadIdx.x & 63;
    int n = blockIdx.x * 4 + wave;
    if (n >= N) return;
    float as2 = att_s2[0], ad2 = att_d2[0];
    int beg = off[n], end = off[n + 1];
    float dstterm = z[n] * ad2;
    float m = -1e30f, s = 0.f, w = 0.f;
    for (int i = beg + lane; i < end; i += 64) {
        int sN = esrc[i];
        float zv = z[sN];
        float ev = zv * as2 + dstterm;
        ev = ev > 0.f ? ev : NEG_SLOPE * ev;
        float nm = fmaxf(m, ev);
        float c0 = __expf(m - nm), c1 = __expf(ev - nm);
        s = s * c0 + c1;
        w = w * c0 + c1 * zv;
        m = nm;
    }
    #pragma unroll
    for (int o = 32; o > 0; o >>= 1) {
        float om = __shfl_xor(m, o), os = __shfl_xor(s, o), ow = __shfl_xor(w, o);
        float nm = fmaxf(m, om);
        float c0 = __expf(m - nm), c1 = __expf(om - nm);
        s = s * c0 + os * c1;
        w = w * c0 + ow * c1;
        m = nm;
    }
    if (lane == 0) out[n] = w / s + bias2[0];
}

// ---------------- launch ----------------
extern "C" void kernel_launch(void* const* d_in, const int* in_sizes, int n_in,
                              void* d_out, int out_size, void* d_ws, size_t ws_size,
                              hipStream_t stream)
{
    const float* x        = (const float*)d_in[0];
    const int*   ei       = (const int*)d_in[1];
    const float* W1       = (const float*)d_in[2];
    const float* att_src1 = (const float*)d_in[3];
    const float* att_dst1 = (const float*)d_in[4];
    const float* bias1    = (const float*)d_in[5];
    const float* W2       = (const float*)d_in[6];
    const float* att_src2 = (const float*)d_in[7];
    const float* att_dst2 = (const float*)d_in[8];
    const float* bias2    = (const float*)d_in[9];
    float* out = (float*)d_out;

    int N = in_sizes[0] / INC;
    int E = in_sizes[1] / 2;
    int Etot = E + N;

    char* p = (char*)d_ws;
    auto alloc = [&](size_t bytes) {
        void* r = (void*)p;
        p += (bytes + 255) & ~(size_t)255;
        return r;
    };
    float* h1     = (float*)alloc((size_t)N * F1 * 4);
    float* a_src1 = (float*)alloc((size_t)N * HEADS * 4);
    float* a_dst1 = (float*)alloc((size_t)N * HEADS * 4);
    float* z      = (float*)alloc((size_t)N * 4);
    int* deg    = (int*)alloc((size_t)N * 4);
    int* incl   = (int*)alloc((size_t)N * 4);
    int* off    = (int*)alloc((size_t)(N + 1) * 4);
    int* cursor = (int*)alloc((size_t)N * 4);
    int* bsum   = (int*)alloc(1024);
    int* esrc   = (int*)alloc((size_t)Etot * 4);

    hipMemsetAsync(deg, 0, (size_t)N * 4, stream);

    int nrt = (N + BM - 1) / BM;
    gemm1_kernel<<<nrt, 256, 0, stream>>>(x, W1, att_src1, att_dst1, h1, a_src1, a_dst1, N);

    int egrid = (Etot + 255) / 256;
    hist_kernel<<<egrid, 256, 0, stream>>>(ei, deg, E, Etot);

    int nb = (N + 255) / 256;
    scan1_kernel<<<nb, 256, 0, stream>>>(deg, incl, bsum, N);
    scan2_kernel<<<1, 256, 0, stream>>>(bsum, nb);
    int nb1 = (N + 1 + 255) / 256;
    scan3_kernel<<<nb1, 256, 0, stream>>>(deg, incl, bsum, off, cursor, N, Etot);
    fill_kernel<<<egrid, 256, 0, stream>>>(ei, cursor, esrc, E, Etot);

    int ngrid1 = (N + 3) / 4;
    agg1_kernel<<<ngrid1, 256, 0, stream>>>(h1, a_src1, a_dst1, off, esrc, bias1, W2, z, N);

    int ngrid2 = (N + 3) / 4;
    agg2_kernel<<<ngrid2, 256, 0, stream>>>(z, off, esrc, att_src2, att_dst2, bias2, out, N);
}

// Round 3
// 259.634 us; speedup vs baseline: 12.6799x; 1.1864x over previous
//
#include <hip/hip_runtime.h>
#include <hip/hip_fp16.h>
#include <math.h>

#define INC 128
#define F1 256
#define HEADS 4
#define NEG_SLOPE 0.2f
#define BM 32
#define BK 32

// ---------------- GEMM1: h1 = x @ W1 (fp16 out), fused att dot products ----------------
// grid: ceil(N/32) blocks, 256 threads (4 waves). Wave w: rows w*8..w*8+7.
// Lane l: cols l*4..l*4+3. Per-lane acc[8][4].
__global__ __launch_bounds__(256, 4) void gemm1_kernel(
    const float* __restrict__ x, const float* __restrict__ W1,
    const float* __restrict__ att_s, const float* __restrict__ att_d,
    __half* __restrict__ h1, float* __restrict__ a_src, float* __restrict__ a_dst,
    int N)
{
    __shared__ float ws[BK][F1];   // 32 KB
    __shared__ float xs[BK][36];   // transposed x tile, padded

    const int wave = threadIdx.x >> 6;
    const int lane = threadIdx.x & 63;
    const int c4 = lane << 2;
    const int row0 = blockIdx.x * BM;

    float acc[8][4] = {};

    for (int k0 = 0; k0 < INC; k0 += BK) {
        {
            int r = threadIdx.x >> 3;
            int kq = (threadIdx.x & 7) << 2;
            int row = row0 + r;
            float4 v = (row < N) ? *(const float4*)&x[(size_t)row * INC + k0 + kq]
                                 : make_float4(0.f, 0.f, 0.f, 0.f);
            xs[kq + 0][r] = v.x;
            xs[kq + 1][r] = v.y;
            xs[kq + 2][r] = v.z;
            xs[kq + 3][r] = v.w;
        }
        #pragma unroll
        for (int i = 0; i < 8; ++i) {
            int fi = (threadIdx.x + i * 256) << 2;
            int kk = fi >> 8;
            int c = fi & 255;
            *(float4*)&ws[kk][c] = *(const float4*)&W1[(size_t)(k0 + kk) * F1 + c];
        }
        __syncthreads();

        #pragma unroll 4
        for (int kk = 0; kk < BK; ++kk) {
            float4 wv = *(float4*)&ws[kk][c4];
            float4 xa = *(float4*)&xs[kk][wave << 3];
            float4 xb = *(float4*)&xs[kk][(wave << 3) + 4];
            float xr[8] = {xa.x, xa.y, xa.z, xa.w, xb.x, xb.y, xb.z, xb.w};
            #pragma unroll
            for (int r = 0; r < 8; ++r) {
                acc[r][0] = fmaf(xr[r], wv.x, acc[r][0]);
                acc[r][1] = fmaf(xr[r], wv.y, acc[r][1]);
                acc[r][2] = fmaf(xr[r], wv.z, acc[r][2]);
                acc[r][3] = fmaf(xr[r], wv.w, acc[r][3]);
            }
        }
        __syncthreads();
    }

    float4 as4 = *(const float4*)&att_s[c4];
    float4 ad4 = *(const float4*)&att_d[c4];
    int head = lane >> 4;
    #pragma unroll
    for (int r = 0; r < 8; ++r) {
        int row = row0 + (wave << 3) + r;
        if (row >= N) continue;
        __half2 p0 = __floats2half2_rn(acc[r][0], acc[r][1]);
        __half2 p1 = __floats2half2_rn(acc[r][2], acc[r][3]);
        uint2 st;
        st.x = *(unsigned int*)&p0;
        st.y = *(unsigned int*)&p1;
        *(uint2*)&h1[(size_t)row * F1 + c4] = st;
        float ps = acc[r][0] * as4.x + acc[r][1] * as4.y + acc[r][2] * as4.z + acc[r][3] * as4.w;
        float pd = acc[r][0] * ad4.x + acc[r][1] * ad4.y + acc[r][2] * ad4.z + acc[r][3] * ad4.w;
        #pragma unroll
        for (int o = 8; o > 0; o >>= 1) {
            ps += __shfl_xor(ps, o);
            pd += __shfl_xor(pd, o);
        }
        if ((lane & 15) == 0) {
            a_src[row * HEADS + head] = ps;
            a_dst[row * HEADS + head] = pd;
        }
    }
}

// ---------------- CSR build ----------------
__global__ void hist_kernel(const int* __restrict__ ei, int* __restrict__ deg,
                            int E, int Etot)
{
    int e = blockIdx.x * blockDim.x + threadIdx.x;
    if (e >= Etot) return;
    int d = (e < E) ? ei[E + e] : (e - E);
    atomicAdd(&deg[d], 1);
}

__global__ void scan1_kernel(const int* __restrict__ deg, int* __restrict__ incl,
                             int* __restrict__ bsum, int N)
{
    __shared__ int tmp[256];
    int i = blockIdx.x * 256 + threadIdx.x;
    int v = (i < N) ? deg[i] : 0;
    tmp[threadIdx.x] = v;
    __syncthreads();
    for (int o = 1; o < 256; o <<= 1) {
        int add = (threadIdx.x >= o) ? tmp[threadIdx.x - o] : 0;
        __syncthreads();
        tmp[threadIdx.x] += add;
        __syncthreads();
    }
    if (i < N) incl[i] = tmp[threadIdx.x];
    if (threadIdx.x == 255) bsum[blockIdx.x] = tmp[255];
}

__global__ void scan2_kernel(int* __restrict__ bsum, int nb)
{
    __shared__ int tmp[256];
    int v = (threadIdx.x < nb) ? bsum[threadIdx.x] : 0;
    tmp[threadIdx.x] = v;
    __syncthreads();
    for (int o = 1; o < 256; o <<= 1) {
        int add = (threadIdx.x >= o) ? tmp[threadIdx.x - o] : 0;
        __syncthreads();
        tmp[threadIdx.x] += add;
        __syncthreads();
    }
    if (threadIdx.x < nb) bsum[threadIdx.x] = tmp[threadIdx.x] - v;  // exclusive
}

__global__ void scan3_kernel(const int* __restrict__ deg, const int* __restrict__ incl,
                             const int* __restrict__ bsum, int* __restrict__ off,
                             int* __restrict__ cursor, int N, int Etot)
{
    int i = blockIdx.x * 256 + threadIdx.x;
    if (i < N) {
        int ex = incl[i] - deg[i] + bsum[blockIdx.x];
        off[i] = ex;
        cursor[i] = ex;
    } else if (i == N) {
        off[N] = Etot;
    }
}

__global__ void fill_kernel(const int* __restrict__ ei, int* __restrict__ cursor,
                            int* __restrict__ esrc, int E, int Etot)
{
    int e = blockIdx.x * blockDim.x + threadIdx.x;
    if (e >= Etot) return;
    int s, d;
    if (e < E) { s = ei[e]; d = ei[E + e]; }
    else       { s = d = e - E; }
    int pos = atomicAdd(&cursor[d], 1);
    esrc[pos] = s;
}

// ---------------- Layer-1 aggregation + bias + ELU + z = out1 @ W2 ----------------
// One WAVE per node. Lane l: head = l>>4, channels c4 = l*4 (half4 = 8B load).
__global__ __launch_bounds__(256) void agg1_kernel(
    const __half* __restrict__ h1, const float* __restrict__ a_src,
    const float* __restrict__ a_dst, const int* __restrict__ off,
    const int* __restrict__ esrc, const float* __restrict__ bias1,
    const float* __restrict__ W2, float* __restrict__ z, int N)
{
    const int wave = threadIdx.x >> 6;
    const int lane = threadIdx.x & 63;
    const int n = blockIdx.x * 4 + wave;
    if (n >= N) return;

    const int beg = off[n], end = off[n + 1];
    const float4* a_src4 = (const float4*)a_src;
    const uint2* h2 = (const uint2*)h1;
    float4 ad4 = *(const float4*)&a_dst[n * HEADS];
    float ad[4] = {ad4.x, ad4.y, ad4.z, ad4.w};

    // phase 1: online softmax (max + denom) per head, lane-parallel over edges
    float m[4] = {-1e30f, -1e30f, -1e30f, -1e30f};
    float s[4] = {0.f, 0.f, 0.f, 0.f};
    for (int i = beg + lane; i < end; i += 64) {
        int sN = esrc[i];
        float4 a4 = a_src4[sN];
        float av[4] = {a4.x, a4.y, a4.z, a4.w};
        #pragma unroll
        for (int h = 0; h < 4; ++h) {
            float ev = av[h] + ad[h];
            ev = ev > 0.f ? ev : NEG_SLOPE * ev;
            float nm = fmaxf(m[h], ev);
            s[h] = s[h] * __expf(m[h] - nm) + __expf(ev - nm);
            m[h] = nm;
        }
    }
    #pragma unroll
    for (int o = 32; o > 0; o >>= 1) {
        #pragma unroll
        for (int h = 0; h < 4; ++h) {
            float om = __shfl_xor(m[h], o);
            float os = __shfl_xor(s[h], o);
            float nm = fmaxf(m[h], om);
            s[h] = s[h] * __expf(m[h] - nm) + os * __expf(om - nm);
            m[h] = nm;
        }
    }

    const int head = lane >> 4;
    float mh = m[head];
    float invh = 1.f / s[head];
    float adh = ad[head];

    // phase 2: weighted gather, one h1 row (512 B fp16) per edge
    float acc0 = 0.f, acc1 = 0.f, acc2 = 0.f, acc3 = 0.f;
    #pragma unroll 2
    for (int i = beg; i < end; ++i) {
        int sN = esrc[i];
        float asv = a_src[sN * HEADS + head];
        float ev = asv + adh;
        ev = ev > 0.f ? ev : NEG_SLOPE * ev;
        float al = __expf(ev - mh) * invh;
        uint2 v = h2[(size_t)sN * 64 + lane];
        __half2 h01 = *(__half2*)&v.x;
        __half2 h23 = *(__half2*)&v.y;
        float2 f01 = __half22float2(h01);
        float2 f23 = __half22float2(h23);
        acc0 = fmaf(al, f01.x, acc0);
        acc1 = fmaf(al, f01.y, acc1);
        acc2 = fmaf(al, f23.x, acc2);
        acc3 = fmaf(al, f23.y, acc3);
    }

    // bias + ELU + dot with W2 (out1 never materialized; only z is needed)
    float4 b4 = *(const float4*)&bias1[lane << 2];
    float4 w24 = *(const float4*)&W2[lane << 2];
    float o0 = acc0 + b4.x, o1 = acc1 + b4.y, o2 = acc2 + b4.z, o3 = acc3 + b4.w;
    o0 = o0 > 0.f ? o0 : __expf(o0) - 1.f;
    o1 = o1 > 0.f ? o1 : __expf(o1) - 1.f;
    o2 = o2 > 0.f ? o2 : __expf(o2) - 1.f;
    o3 = o3 > 0.f ? o3 : __expf(o3) - 1.f;
    float p = o0 * w24.x + o1 * w24.y + o2 * w24.z + o3 * w24.w;
    #pragma unroll
    for (int o = 32; o > 0; o >>= 1) p += __shfl_xor(p, o);
    if (lane == 0) z[n] = p;
}

// ---------------- Layer-2 aggregation: one wave per node ----------------
__global__ __launch_bounds__(256) void agg2_kernel(
    const float* __restrict__ z, const int* __restrict__ off,
    const int* __restrict__ esrc, const float* __restrict__ att_s2,
    const float* __restrict__ att_d2, const float* __restrict__ bias2,
    float* __restrict__ out, int N)
{
    int wave = threadIdx.x >> 6;
    int lane = threadIdx.x & 63;
    int n = blockIdx.x * 4 + wave;
    if (n >= N) return;
    float as2 = att_s2[0], ad2 = att_d2[0];
    int beg = off[n], end = off[n + 1];
    float dstterm = z[n] * ad2;
    float m = -1e30f, s = 0.f, w = 0.f;
    for (int i = beg + lane; i < end; i += 64) {
        int sN = esrc[i];
        float zv = z[sN];
        float ev = zv * as2 + dstterm;
        ev = ev > 0.f ? ev : NEG_SLOPE * ev;
        float nm = fmaxf(m, ev);
        float c0 = __expf(m - nm), c1 = __expf(ev - nm);
        s = s * c0 + c1;
        w = w * c0 + c1 * zv;
        m = nm;
    }
    #pragma unroll
    for (int o = 32; o > 0; o >>= 1) {
        float om = __shfl_xor(m, o), os = __shfl_xor(s, o), ow = __shfl_xor(w, o);
        float nm = fmaxf(m, om);
        float c0 = __expf(m - nm), c1 = __expf(om - nm);
        s = s * c0 + os * c1;
        w = w * c0 + ow * c1;
        m = nm;
    }
    if (lane == 0) out[n] = w / s + bias2[0];
}

// ---------------- launch ----------------
extern "C" void kernel_launch(void* const* d_in, const int* in_sizes, int n_in,
                              void* d_out, int out_size, void* d_ws, size_t ws_size,
                              hipStream_t stream)
{
    const float* x        = (const float*)d_in[0];
    const int*   ei       = (const int*)d_in[1];
    const float* W1       = (const float*)d_in[2];
    const float* att_src1 = (const float*)d_in[3];
    const float* att_dst1 = (const float*)d_in[4];
    const float* bias1    = (const float*)d_in[5];
    const float* W2       = (const float*)d_in[6];
    const float* att_src2 = (const float*)d_in[7];
    const float* att_dst2 = (const float*)d_in[8];
    const float* bias2    = (const float*)d_in[9];
    float* out = (float*)d_out;

    int N = in_sizes[0] / INC;
    int E = in_sizes[1] / 2;
    int Etot = E + N;

    char* p = (char*)d_ws;
    auto alloc = [&](size_t bytes) {
        void* r = (void*)p;
        p += (bytes + 255) & ~(size_t)255;
        return r;
    };
    __half* h1    = (__half*)alloc((size_t)N * F1 * 2);
    float* a_src1 = (float*)alloc((size_t)N * HEADS * 4);
    float* a_dst1 = (float*)alloc((size_t)N * HEADS * 4);
    float* z      = (float*)alloc((size_t)N * 4);
    int* deg    = (int*)alloc((size_t)N * 4);
    int* incl   = (int*)alloc((size_t)N * 4);
    int* off    = (int*)alloc((size_t)(N + 1) * 4);
    int* cursor = (int*)alloc((size_t)N * 4);
    int* bsum   = (int*)alloc(1024);
    int* esrc   = (int*)alloc((size_t)Etot * 4);

    hipMemsetAsync(deg, 0, (size_t)N * 4, stream);

    int nrt = (N + BM - 1) / BM;
    gemm1_kernel<<<nrt, 256, 0, stream>>>(x, W1, att_src1, att_dst1, h1, a_src1, a_dst1, N);

    int egrid = (Etot + 255) / 256;
    hist_kernel<<<egrid, 256, 0, stream>>>(ei, deg, E, Etot);

    int nb = (N + 255) / 256;
    scan1_kernel<<<nb, 256, 0, stream>>>(deg, incl, bsum, N);
    scan2_kernel<<<1, 256, 0, stream>>>(bsum, nb);
    int nb1 = (N + 1 + 255) / 256;
    scan3_kernel<<<nb1, 256, 0, stream>>>(deg, incl, bsum, off, cursor, N, Etot);
    fill_kernel<<<egrid, 256, 0, stream>>>(ei, cursor, esrc, E, Etot);

    int ngrid1 = (N + 3) / 4;
    agg1_kernel<<<ngrid1, 256, 0, stream>>>(h1, a_src1, a_dst1, off, esrc, bias1, W2, z, N);

    int ngrid2 = (N + 3) / 4;
    agg2_kernel<<<ngrid2, 256, 0, stream>>>(z, off, esrc, att_src2, att_dst2, bias2, out, N);
}

// Round 4
// 236.671 us; speedup vs baseline: 13.9102x; 1.0970x over previous
//
#include <hip/hip_runtime.h>
#include <hip/hip_fp16.h>
#include <math.h>

#define INC 128
#define F1 256
#define HEADS 4
#define NEG_SLOPE 0.2f
#define BM 32
#define BK 32

// ---------------- GEMM1: h1 = x @ W1 (fp16 out), fused att dot products ----------------
__global__ __launch_bounds__(256, 4) void gemm1_kernel(
    const float* __restrict__ x, const float* __restrict__ W1,
    const float* __restrict__ att_s, const float* __restrict__ att_d,
    __half* __restrict__ h1, float* __restrict__ a_src, float* __restrict__ a_dst,
    int N)
{
    __shared__ float ws[BK][F1];   // 32 KB
    __shared__ float xs[BK][36];   // transposed x tile, padded

    const int wave = threadIdx.x >> 6;
    const int lane = threadIdx.x & 63;
    const int c4 = lane << 2;
    const int row0 = blockIdx.x * BM;

    float acc[8][4] = {};

    for (int k0 = 0; k0 < INC; k0 += BK) {
        {
            int r = threadIdx.x >> 3;
            int kq = (threadIdx.x & 7) << 2;
            int row = row0 + r;
            float4 v = (row < N) ? *(const float4*)&x[(size_t)row * INC + k0 + kq]
                                 : make_float4(0.f, 0.f, 0.f, 0.f);
            xs[kq + 0][r] = v.x;
            xs[kq + 1][r] = v.y;
            xs[kq + 2][r] = v.z;
            xs[kq + 3][r] = v.w;
        }
        #pragma unroll
        for (int i = 0; i < 8; ++i) {
            int fi = (threadIdx.x + i * 256) << 2;
            int kk = fi >> 8;
            int c = fi & 255;
            *(float4*)&ws[kk][c] = *(const float4*)&W1[(size_t)(k0 + kk) * F1 + c];
        }
        __syncthreads();

        #pragma unroll 4
        for (int kk = 0; kk < BK; ++kk) {
            float4 wv = *(float4*)&ws[kk][c4];
            float4 xa = *(float4*)&xs[kk][wave << 3];
            float4 xb = *(float4*)&xs[kk][(wave << 3) + 4];
            float xr[8] = {xa.x, xa.y, xa.z, xa.w, xb.x, xb.y, xb.z, xb.w};
            #pragma unroll
            for (int r = 0; r < 8; ++r) {
                acc[r][0] = fmaf(xr[r], wv.x, acc[r][0]);
                acc[r][1] = fmaf(xr[r], wv.y, acc[r][1]);
                acc[r][2] = fmaf(xr[r], wv.z, acc[r][2]);
                acc[r][3] = fmaf(xr[r], wv.w, acc[r][3]);
            }
        }
        __syncthreads();
    }

    float4 as4 = *(const float4*)&att_s[c4];
    float4 ad4 = *(const float4*)&att_d[c4];
    int head = lane >> 4;
    #pragma unroll
    for (int r = 0; r < 8; ++r) {
        int row = row0 + (wave << 3) + r;
        if (row >= N) continue;
        __half2 p0 = __floats2half2_rn(acc[r][0], acc[r][1]);
        __half2 p1 = __floats2half2_rn(acc[r][2], acc[r][3]);
        uint2 st;
        st.x = *(unsigned int*)&p0;
        st.y = *(unsigned int*)&p1;
        *(uint2*)&h1[(size_t)row * F1 + c4] = st;
        float ps = acc[r][0] * as4.x + acc[r][1] * as4.y + acc[r][2] * as4.z + acc[r][3] * as4.w;
        float pd = acc[r][0] * ad4.x + acc[r][1] * ad4.y + acc[r][2] * ad4.z + acc[r][3] * ad4.w;
        #pragma unroll
        for (int o = 8; o > 0; o >>= 1) {
            ps += __shfl_xor(ps, o);
            pd += __shfl_xor(pd, o);
        }
        if ((lane & 15) == 0) {
            a_src[row * HEADS + head] = ps;
            a_dst[row * HEADS + head] = pd;
        }
    }
}

// ---------------- CSR build ----------------
__global__ void hist_kernel(const int* __restrict__ ei, int* __restrict__ deg,
                            int E, int Etot)
{
    int e = blockIdx.x * blockDim.x + threadIdx.x;
    if (e >= Etot) return;
    int d = (e < E) ? ei[E + e] : (e - E);
    atomicAdd(&deg[d], 1);
}

__global__ void scan1_kernel(const int* __restrict__ deg, int* __restrict__ incl,
                             int* __restrict__ bsum, int N)
{
    __shared__ int tmp[256];
    int i = blockIdx.x * 256 + threadIdx.x;
    int v = (i < N) ? deg[i] : 0;
    tmp[threadIdx.x] = v;
    __syncthreads();
    for (int o = 1; o < 256; o <<= 1) {
        int add = (threadIdx.x >= o) ? tmp[threadIdx.x - o] : 0;
        __syncthreads();
        tmp[threadIdx.x] += add;
        __syncthreads();
    }
    if (i < N) incl[i] = tmp[threadIdx.x];
    if (threadIdx.x == 255) bsum[blockIdx.x] = tmp[255];
}

__global__ void scan2_kernel(int* __restrict__ bsum, int nb)
{
    __shared__ int tmp[256];
    int v = (threadIdx.x < nb) ? bsum[threadIdx.x] : 0;
    tmp[threadIdx.x] = v;
    __syncthreads();
    for (int o = 1; o < 256; o <<= 1) {
        int add = (threadIdx.x >= o) ? tmp[threadIdx.x - o] : 0;
        __syncthreads();
        tmp[threadIdx.x] += add;
        __syncthreads();
    }
    if (threadIdx.x < nb) bsum[threadIdx.x] = tmp[threadIdx.x] - v;  // exclusive
}

__global__ void scan3_kernel(const int* __restrict__ deg, const int* __restrict__ incl,
                             const int* __restrict__ bsum, int* __restrict__ off,
                             int* __restrict__ cursor, int N, int Etot)
{
    int i = blockIdx.x * 256 + threadIdx.x;
    if (i < N) {
        int ex = incl[i] - deg[i] + bsum[blockIdx.x];
        off[i] = ex;
        cursor[i] = ex;
    } else if (i == N) {
        off[N] = Etot;
    }
}

__global__ void fill_kernel(const int* __restrict__ ei, int* __restrict__ cursor,
                            int* __restrict__ esrc, int E, int Etot)
{
    int e = blockIdx.x * blockDim.x + threadIdx.x;
    if (e >= Etot) return;
    int s, d;
    if (e < E) { s = ei[e]; d = ei[E + e]; }
    else       { s = d = e - E; }
    int pos = atomicAdd(&cursor[d], 1);
    esrc[pos] = s;
}

// ---------------- Layer-1 aggregation + bias + ELU + z = out1 @ W2 ----------------
// One WAVE per node. Phase 2a: lane i computes alpha[4] for edge chunk+i once,
// stashes in per-wave LDS. Phase 2b: broadcast-read alpha, pure gather+fma.
__global__ __launch_bounds__(256) void agg1_kernel(
    const __half* __restrict__ h1, const float* __restrict__ a_src,
    const float* __restrict__ a_dst, const int* __restrict__ off,
    const int* __restrict__ esrc, const float* __restrict__ bias1,
    const float* __restrict__ W2, float* __restrict__ z, int N)
{
    __shared__ float lalpha[4][64][4];  // [wave][edge][head] 4 KB
    __shared__ int   lsrc[4][64];       // 1 KB

    const int wave = threadIdx.x >> 6;
    const int lane = threadIdx.x & 63;
    const int n = blockIdx.x * 4 + wave;
    if (n >= N) return;

    const int beg = off[n], end = off[n + 1];
    const float4* a_src4 = (const float4*)a_src;
    const uint2* h2 = (const uint2*)h1;
    float4 ad4 = *(const float4*)&a_dst[n * HEADS];
    float ad[4] = {ad4.x, ad4.y, ad4.z, ad4.w};

    // phase 1: online softmax (max + denom) per head, lane-parallel over edges
    float m[4] = {-1e30f, -1e30f, -1e30f, -1e30f};
    float s[4] = {0.f, 0.f, 0.f, 0.f};
    for (int i = beg + lane; i < end; i += 64) {
        int sN = esrc[i];
        float4 a4 = a_src4[sN];
        float av[4] = {a4.x, a4.y, a4.z, a4.w};
        #pragma unroll
        for (int h = 0; h < 4; ++h) {
            float ev = av[h] + ad[h];
            ev = ev > 0.f ? ev : NEG_SLOPE * ev;
            float nm = fmaxf(m[h], ev);
            s[h] = s[h] * __expf(m[h] - nm) + __expf(ev - nm);
            m[h] = nm;
        }
    }
    #pragma unroll
    for (int o = 32; o > 0; o >>= 1) {
        #pragma unroll
        for (int h = 0; h < 4; ++h) {
            float om = __shfl_xor(m[h], o);
            float os = __shfl_xor(s[h], o);
            float nm = fmaxf(m[h], om);
            s[h] = s[h] * __expf(m[h] - nm) + os * __expf(om - nm);
            m[h] = nm;
        }
    }
    float inv[4];
    #pragma unroll
    for (int h = 0; h < 4; ++h) inv[h] = 1.f / s[h];

    const int head = lane >> 4;
    float acc0 = 0.f, acc1 = 0.f, acc2 = 0.f, acc3 = 0.f;

    for (int c0 = beg; c0 < end; c0 += 64) {
        int i = c0 + lane;
        // 2a: one lane per edge computes alpha for all 4 heads (4 exps/edge total)
        if (i < end) {
            int sN = esrc[i];
            float4 a4 = a_src4[sN];
            float av[4] = {a4.x, a4.y, a4.z, a4.w};
            #pragma unroll
            for (int h = 0; h < 4; ++h) {
                float ev = av[h] + ad[h];
                ev = ev > 0.f ? ev : NEG_SLOPE * ev;
                lalpha[wave][lane][h] = __expf(ev - m[h]) * inv[h];
            }
            lsrc[wave][lane] = sN;
        }
        // same-wave LDS producer/consumer: in-order per wave, no barrier needed
        int cend = end - c0;
        if (cend > 64) cend = 64;
        // 2b: pure gather
        #pragma unroll 2
        for (int j = 0; j < cend; ++j) {
            float al = lalpha[wave][j][head];
            int sN = lsrc[wave][j];
            uint2 v = h2[(size_t)sN * 64 + lane];
            __half2 h01 = *(__half2*)&v.x;
            __half2 h23 = *(__half2*)&v.y;
            float2 f01 = __half22float2(h01);
            float2 f23 = __half22float2(h23);
            acc0 = fmaf(al, f01.x, acc0);
            acc1 = fmaf(al, f01.y, acc1);
            acc2 = fmaf(al, f23.x, acc2);
            acc3 = fmaf(al, f23.y, acc3);
        }
    }

    // bias + ELU + dot with W2 (out1 never materialized; only z is needed)
    float4 b4 = *(const float4*)&bias1[lane << 2];
    float4 w24 = *(const float4*)&W2[lane << 2];
    float o0 = acc0 + b4.x, o1 = acc1 + b4.y, o2 = acc2 + b4.z, o3 = acc3 + b4.w;
    o0 = o0 > 0.f ? o0 : __expf(o0) - 1.f;
    o1 = o1 > 0.f ? o1 : __expf(o1) - 1.f;
    o2 = o2 > 0.f ? o2 : __expf(o2) - 1.f;
    o3 = o3 > 0.f ? o3 : __expf(o3) - 1.f;
    float p = o0 * w24.x + o1 * w24.y + o2 * w24.z + o3 * w24.w;
    #pragma unroll
    for (int o = 32; o > 0; o >>= 1) p += __shfl_xor(p, o);
    if (lane == 0) z[n] = p;
}

// ---------------- Layer-2 aggregation: one wave per node ----------------
__global__ __launch_bounds__(256) void agg2_kernel(
    const float* __restrict__ z, const int* __restrict__ off,
    const int* __restrict__ esrc, const float* __restrict__ att_s2,
    const float* __restrict__ att_d2, const float* __restrict__ bias2,
    float* __restrict__ out, int N)
{
    int wave = threadIdx.x >> 6;
    int lane = threadIdx.x & 63;
    int n = blockIdx.x * 4 + wave;
    if (n >= N) return;
    float as2 = att_s2[0], ad2 = att_d2[0];
    int beg = off[n], end = off[n + 1];
    float dstterm = z[n] * ad2;
    float m = -1e30f, s = 0.f, w = 0.f;
    for (int i = beg + lane; i < end; i += 64) {
        int sN = esrc[i];
        float zv = z[sN];
        float ev = zv * as2 + dstterm;
        ev = ev > 0.f ? ev : NEG_SLOPE * ev;
        float nm = fmaxf(m, ev);
        float c0 = __expf(m - nm), c1 = __expf(ev - nm);
        s = s * c0 + c1;
        w = w * c0 + c1 * zv;
        m = nm;
    }
    #pragma unroll
    for (int o = 32; o > 0; o >>= 1) {
        float om = __shfl_xor(m, o), os = __shfl_xor(s, o), ow = __shfl_xor(w, o);
        float nm = fmaxf(m, om);
        float c0 = __expf(m - nm), c1 = __expf(om - nm);
        s = s * c0 + os * c1;
        w = w * c0 + ow * c1;
        m = nm;
    }
    if (lane == 0) out[n] = w / s + bias2[0];
}

// ---------------- launch ----------------
extern "C" void kernel_launch(void* const* d_in, const int* in_sizes, int n_in,
                              void* d_out, int out_size, void* d_ws, size_t ws_size,
                              hipStream_t stream)
{
    const float* x        = (const float*)d_in[0];
    const int*   ei       = (const int*)d_in[1];
    const float* W1       = (const float*)d_in[2];
    const float* att_src1 = (const float*)d_in[3];
    const float* att_dst1 = (const float*)d_in[4];
    const float* bias1    = (const float*)d_in[5];
    const float* W2       = (const float*)d_in[6];
    const float* att_src2 = (const float*)d_in[7];
    const float* att_dst2 = (const float*)d_in[8];
    const float* bias2    = (const float*)d_in[9];
    float* out = (float*)d_out;

    int N = in_sizes[0] / INC;
    int E = in_sizes[1] / 2;
    int Etot = E + N;

    char* p = (char*)d_ws;
    auto alloc = [&](size_t bytes) {
        void* r = (void*)p;
        p += (bytes + 255) & ~(size_t)255;
        return r;
    };
    __half* h1    = (__half*)alloc((size_t)N * F1 * 2);
    float* a_src1 = (float*)alloc((size_t)N * HEADS * 4);
    float* a_dst1 = (float*)alloc((size_t)N * HEADS * 4);
    float* z      = (float*)alloc((size_t)N * 4);
    int* deg    = (int*)alloc((size_t)N * 4);
    int* incl   = (int*)alloc((size_t)N * 4);
    int* off    = (int*)alloc((size_t)(N + 1) * 4);
    int* cursor = (int*)alloc((size_t)N * 4);
    int* bsum   = (int*)alloc(1024);
    int* esrc   = (int*)alloc((size_t)Etot * 4);

    hipMemsetAsync(deg, 0, (size_t)N * 4, stream);

    int nrt = (N + BM - 1) / BM;
    gemm1_kernel<<<nrt, 256, 0, stream>>>(x, W1, att_src1, att_dst1, h1, a_src1, a_dst1, N);

    int egrid = (Etot + 255) / 256;
    hist_kernel<<<egrid, 256, 0, stream>>>(ei, deg, E, Etot);

    int nb = (N + 255) / 256;
    scan1_kernel<<<nb, 256, 0, stream>>>(deg, incl, bsum, N);
    scan2_kernel<<<1, 256, 0, stream>>>(bsum, nb);
    int nb1 = (N + 1 + 255) / 256;
    scan3_kernel<<<nb1, 256, 0, stream>>>(deg, incl, bsum, off, cursor, N, Etot);
    fill_kernel<<<egrid, 256, 0, stream>>>(ei, cursor, esrc, E, Etot);

    int ngrid1 = (N + 3) / 4;
    agg1_kernel<<<ngrid1, 256, 0, stream>>>(h1, a_src1, a_dst1, off, esrc, bias1, W2, z, N);

    int ngrid2 = (N + 3) / 4;
    agg2_kernel<<<ngrid2, 256, 0, stream>>>(z, off, esrc, att_src2, att_dst2, bias2, out, N);
}